// Round 4
// baseline (713.887 us; speedup 1.0000x reference)
//
#include <hip/hip_runtime.h>

// AdaptSelfAttention: B=4, S=320, H=512, NH=8, DH=64
// B_D = (qv @ Wr_slice) . rpe  -> stream rpe once (839MB, HBM-bound)
// k1: q/v projections -> qu, qv, valp
// k4: prologue (w = qv@Wr into LDS scratch); stream rpe (swizzled gl_lds,
//     double-buffered) with per-tile fused A_C+rand+c+mask for the NEXT
//     tile's k-slice; softmax; PV.  XCD-swizzled flat grid (one b per XCD).

#define NEGV (-1e15f)

typedef unsigned int u32;

__device__ __forceinline__ void gl_lds16(const float* g, float* l) {
  __builtin_amdgcn_global_load_lds(
      (const __attribute__((address_space(1))) u32*)(g),
      (__attribute__((address_space(3))) u32*)(l), 16, 0, 0);
}

__device__ __forceinline__ float dot4f(const float4 a, const float4 b) {
  return a.x*b.x + a.y*b.y + a.z*b.z + a.w*b.w;
}

// ---------------- K1: q/v projections -> qu, qv, valp ----------------
__global__ __launch_bounds__(256) void k1_proj(
    const float* __restrict__ query, const float* __restrict__ value,
    const float* __restrict__ Wq, const float* __restrict__ bq,
    const float* __restrict__ Wv, const float* __restrict__ bv,
    const float* __restrict__ u, const float* __restrict__ v,
    float* __restrict__ qu, float* __restrict__ qv, float* __restrict__ valp)
{
  const int rt = blockIdx.x;      // 0..79 (16 rows)
  const int ct = blockIdx.y;      // 0..3 (128 cols)
  const int which = blockIdx.z;   // 0: query, 1: value
  const int t = threadIdx.x;
  const int R0 = rt * 16;

  __shared__ float xs[16][516];

  const float* X = which ? value : query;
  const float* W = which ? Wv : Wq;
  const float* bias = which ? bv : bq;

  #pragma unroll
  for (int j = 0; j < 8; ++j) {
    int f4 = t + 256 * j;
    int row = f4 >> 7, c4 = f4 & 127;
    float4 xv = *reinterpret_cast<const float4*>(X + (size_t)(R0 + row) * 512 + c4 * 4);
    *reinterpret_cast<float4*>(&xs[row][c4 * 4]) = xv;
  }
  __syncthreads();

  const int r = t >> 4, clo = t & 15;
  #pragma unroll
  for (int sub = 0; sub < 2; ++sub) {
    const int cb = ct * 128 + sub * 64 + clo * 4;
    float a0 = 0.f, a1 = 0.f, a2 = 0.f, a3 = 0.f;
    const float* w0p = W + (size_t)(cb + 0) * 512;
    const float* w1p = W + (size_t)(cb + 1) * 512;
    const float* w2p = W + (size_t)(cb + 2) * 512;
    const float* w3p = W + (size_t)(cb + 3) * 512;
    #pragma unroll 2
    for (int m4 = 0; m4 < 128; ++m4) {
      float4 x4 = *reinterpret_cast<const float4*>(&xs[r][m4 * 4]);
      float4 w0 = *reinterpret_cast<const float4*>(w0p + m4 * 4);
      float4 w1 = *reinterpret_cast<const float4*>(w1p + m4 * 4);
      float4 w2 = *reinterpret_cast<const float4*>(w2p + m4 * 4);
      float4 w3 = *reinterpret_cast<const float4*>(w3p + m4 * 4);
      a0 += dot4f(x4, w0);
      a1 += dot4f(x4, w1);
      a2 += dot4f(x4, w2);
      a3 += dot4f(x4, w3);
    }
    a0 += bias[cb + 0]; a1 += bias[cb + 1]; a2 += bias[cb + 2]; a3 += bias[cb + 3];
    const size_t ob = (size_t)(R0 + r) * 512 + cb;
    if (which == 0) {
      float4 o1, o2;
      o1.x = a0 + u[cb + 0]; o1.y = a1 + u[cb + 1]; o1.z = a2 + u[cb + 2]; o1.w = a3 + u[cb + 3];
      o2.x = a0 + v[cb + 0]; o2.y = a1 + v[cb + 1]; o2.z = a2 + v[cb + 2]; o2.w = a3 + v[cb + 3];
      *reinterpret_cast<float4*>(qu + ob) = o1;
      *reinterpret_cast<float4*>(qv + ob) = o2;
    } else {
      float4 o; o.x = a0; o.y = a1; o.z = a2; o.w = a3;
      *reinterpret_cast<float4*>(valp + ob) = o;
    }
  }
}

// ---------------- K4: fused prologue + rpe stream (A_C in-loop) + softmax + PV ----------------
// flat grid 1280, XCD-swizzled: xcd=blk&7 -> b=xcd>>1, q=(xcd&1)*160+(blk>>3).
// 256 threads. Wave w owns heads {2w,2w+1}. Tile = 16 k-rows, double-buffered.
__global__ __launch_bounds__(256, 2) void k4_attn(
    const float* __restrict__ rpe, const float* __restrict__ key,
    const float* __restrict__ Wr, const float* __restrict__ br,
    const float* __restrict__ rand_attn,
    const int* __restrict__ seq_len, const int* __restrict__ lex_num,
    const float* __restrict__ qu, const float* __restrict__ qv,
    const float* __restrict__ valp,
    float* __restrict__ out)
{
  const int xcd = blockIdx.x & 7;
  const int idx = blockIdx.x >> 3;          // 0..159
  const int b = xcd >> 1;
  const int q = (xcd & 1) * 160 + idx;
  const int t = threadIdx.x;
  const int w = t >> 6;          // wave 0..3 -> heads 2w, 2w+1
  const int lane = t & 63;
  const int row8 = lane >> 3;    // 0..7
  const int chunk = lane & 7;    // 64-e chunk

  __shared__ float bufA[2][16][512];   // 64 KB, swizzled storage
  __shared__ float sc[8][320];

  const size_t bq = (size_t)b * 320 + q;
  const float* rpe_bq = rpe + bq * 320 * 512;
  float* wscr = &bufA[1][0][0];        // 16 KB scratch for w[8][512] (prologue only)

  // staging source offsets (inverse swizzle), 8 per thread
  int g[8];
  #pragma unroll
  for (int j = 0; j < 8; ++j) {
    int o = (w * 8 + j) * 1024 + lane * 16;   // dest byte in 32KB tile
    int row = o >> 11;
    int ch  = (o >> 8) & 7;
    int win = (o >> 7) & 1;
    int slot = (o >> 4) & 7;
    int i = win * 8 + (slot ^ ((row ^ ch) & 7));
    g[j] = row * 512 + (ch * 16 + i) * 4;     // source float offset
  }

  // stage tile 0 (async; does not touch bufA[1])
  #pragma unroll
  for (int j = 0; j < 8; ++j)
    gl_lds16(rpe_bq + g[j], &bufA[0][0][0] + (w * 8 + j) * 256);

  // ---------------- prologue ----------------
  const int hh = t >> 5, m = t & 31;           // thread -> (head, slot)
  const float* qv_row = qv + bq * 512 + hh * 64;

  // (1) w[hh][m*16 .. m*16+15] = sum_d qv_row[d] * Wr[hh*64+d][e]
  {
    float4 a4[4];
    #pragma unroll
    for (int ii = 0; ii < 4; ++ii) { a4[ii].x = 0.f; a4[ii].y = 0.f; a4[ii].z = 0.f; a4[ii].w = 0.f; }
    const float* wrb = Wr + (size_t)(hh * 64) * 512 + m * 16;
    #pragma unroll 4
    for (int d = 0; d < 64; ++d) {
      float s = qv_row[d];
      const float4* w4 = reinterpret_cast<const float4*>(wrb + (size_t)d * 512);
      #pragma unroll
      for (int ii = 0; ii < 4; ++ii) {
        a4[ii].x += s * w4[ii].x; a4[ii].y += s * w4[ii].y;
        a4[ii].z += s * w4[ii].z; a4[ii].w += s * w4[ii].w;
      }
    }
    #pragma unroll
    for (int ii = 0; ii < 4; ++ii)
      *reinterpret_cast<float4*>(wscr + hh * 512 + m * 16 + ii * 4) = a4[ii];
  }

  // (2) c = qv_row . br_slice
  float c = 0.f;
  #pragma unroll 8
  for (int d = 0; d < 64; ++d) c += qv_row[d] * br[hh * 64 + d];

  const int len = seq_len[b] + lex_num[0];
  const float* qup    = qu + bq * 512 + hh * 64 + (m >> 4) * 32;
  const float* keyb   = key + (size_t)b * 320 * 512 + hh * 64 + (m >> 4) * 32;
  const float* rnd_hq = rand_attn + ((size_t)hh * 320 + q) * 320;

  // (3) A_C + rand + c + mask init for tile 0's k-slice [0,16)
  {
    const int kk = m & 15;
    float a = 0.f;
    const float* kr = keyb + (size_t)kk * 512;
    #pragma unroll
    for (int ii = 0; ii < 8; ++ii)
      a += dot4f(reinterpret_cast<const float4*>(qup)[ii],
                 reinterpret_cast<const float4*>(kr)[ii]);
    a += __shfl_xor(a, 16, 32);
    if (m < 16)
      sc[hh][kk] = (kk < len) ? a + rnd_hq[kk] + c : NEGV;
  }
  __syncthreads();   // wscr + sc[0..16) visible; tile-0 staged (vmcnt drain)

  // (4) read w fragments: 2 heads x 16 float4 (this lane's 64-e chunk)
  const int h0 = 2 * w, h1 = 2 * w + 1;
  float4 wc0[16], wc1[16];
  #pragma unroll
  for (int i = 0; i < 16; ++i) {
    wc0[i] = *reinterpret_cast<const float4*>(wscr + h0 * 512 + chunk * 64 + i * 4);
    wc1[i] = *reinterpret_cast<const float4*>(wscr + h1 * 512 + chunk * 64 + i * 4);
  }
  __syncthreads();   // all w reads done before tile-1 staging overwrites bufA[1]

  // ---------------- main streaming loop over 20 tiles of 16 k-rows ----------------
  const int rc = (row8 ^ chunk) & 7;
  const int Cb0 = row8 * 2048 + chunk * 256 + rc * 16;
  const char* bufbase = reinterpret_cast<const char*>(&bufA[0][0][0]);

  int cb = 0;
  for (int tile = 0; tile < 20; ++tile) {
    if (tile + 1 < 20) {
      const float* src = rpe_bq + (size_t)(tile + 1) * 8192;
      float* dst = &bufA[cb ^ 1][0][0];
      #pragma unroll
      for (int j = 0; j < 8; ++j)
        gl_lds16(src + g[j], dst + (w * 8 + j) * 256);
    }

    // B_D for tile's k-slice [16*tile, 16*tile+16)
    const char* bufc = bufbase + cb * 32768;
    #pragma unroll
    for (int pass = 0; pass < 2; ++pass) {
      const int C = Cb0 + pass * 16384;
      float a0 = 0.f, a1 = 0.f;
      #pragma unroll
      for (int i = 0; i < 16; ++i) {
        const float4 r4 = *reinterpret_cast<const float4*>(bufc + (C ^ (i << 4)));
        a0 += dot4f(r4, wc0[i]);
        a1 += dot4f(r4, wc1[i]);
      }
      a0 += __shfl_xor(a0, 1, 8);
      a0 += __shfl_xor(a0, 2, 8);
      a0 += __shfl_xor(a0, 4, 8);
      a1 += __shfl_xor(a1, 1, 8);
      a1 += __shfl_xor(a1, 2, 8);
      a1 += __shfl_xor(a1, 4, 8);
      if (chunk == 0) {
        const int kk = tile * 16 + pass * 8 + row8;
        sc[h0][kk] += a0;
        sc[h1][kk] += a1;
      }
    }

    // A_C + rand + c + mask init for NEXT tile's k-slice (disjoint -> no race)
    if (tile + 1 < 20) {
      const int kk = (tile + 1) * 16 + (m & 15);
      float a = 0.f;
      const float* kr = keyb + (size_t)kk * 512;
      #pragma unroll
      for (int ii = 0; ii < 8; ++ii)
        a += dot4f(reinterpret_cast<const float4*>(qup)[ii],
                   reinterpret_cast<const float4*>(kr)[ii]);
      a += __shfl_xor(a, 16, 32);
      if (m < 16)
        sc[hh][kk] = (kk < len) ? a + rnd_hq[kk] + c : NEGV;
    }

    __syncthreads();
    cb ^= 1;
  }

  // ------- softmax per head row -------
  {
    float vals[10];
    float mx = -3.0e38f;
    #pragma unroll
    for (int i = 0; i < 10; ++i) { vals[i] = sc[hh][m + 32 * i]; mx = fmaxf(mx, vals[i]); }
    mx = fmaxf(mx, __shfl_xor(mx, 1, 32));
    mx = fmaxf(mx, __shfl_xor(mx, 2, 32));
    mx = fmaxf(mx, __shfl_xor(mx, 4, 32));
    mx = fmaxf(mx, __shfl_xor(mx, 8, 32));
    mx = fmaxf(mx, __shfl_xor(mx, 16, 32));
    float s = 0.f;
    #pragma unroll
    for (int i = 0; i < 10; ++i) { vals[i] = __expf(vals[i] - mx); s += vals[i]; }
    s += __shfl_xor(s, 1, 32);
    s += __shfl_xor(s, 2, 32);
    s += __shfl_xor(s, 4, 32);
    s += __shfl_xor(s, 8, 32);
    s += __shfl_xor(s, 16, 32);
    const float inv = 1.0f / s;
    #pragma unroll
    for (int i = 0; i < 10; ++i) sc[hh][m + 32 * i] = vals[i] * inv;
  }
  __syncthreads();

  // ------- PV -------
  {
    const int d2 = m;   // d = 2*d2
    float2 a0; a0.x = 0.f; a0.y = 0.f;
    float2 a1; a1.x = 0.f; a1.y = 0.f;
    const float* vb = valp + (size_t)b * 320 * 512 + hh * 64 + d2 * 2;
    #pragma unroll 4
    for (int k = 0; k < 320; k += 2) {
      float p0 = sc[hh][k], p1 = sc[hh][k + 1];
      float2 v0 = *reinterpret_cast<const float2*>(vb + (size_t)k * 512);
      float2 v1 = *reinterpret_cast<const float2*>(vb + (size_t)(k + 1) * 512);
      a0.x += p0 * v0.x; a0.y += p0 * v0.y;
      a1.x += p1 * v1.x; a1.y += p1 * v1.y;
    }
    float2 o; o.x = a0.x + a1.x; o.y = a0.y + a1.y;
    *reinterpret_cast<float2*>(out + bq * 512 + hh * 64 + d2 * 2) = o;
  }
}

extern "C" void kernel_launch(void* const* d_in, const int* in_sizes, int n_in,
                              void* d_out, int out_size, void* d_ws, size_t ws_size,
                              hipStream_t stream) {
  const float* query = (const float*)d_in[0];
  const float* key   = (const float*)d_in[1];
  const float* value = (const float*)d_in[2];
  const float* rpe   = (const float*)d_in[3];
  const int*   seq_len = (const int*)d_in[4];
  const int*   lex_num = (const int*)d_in[5];
  const float* Wq = (const float*)d_in[6];
  const float* bq = (const float*)d_in[7];
  const float* Wv = (const float*)d_in[8];
  const float* bv = (const float*)d_in[9];
  const float* Wr = (const float*)d_in[10];
  const float* br = (const float*)d_in[11];
  const float* u  = (const float*)d_in[12];
  const float* v  = (const float*)d_in[13];
  const float* rnd = (const float*)d_in[14];

  float* out = (float*)d_out;
  float* ws = (float*)d_ws;
  float* qu    = ws;                 // 655360 floats
  float* qv    = ws + 655360;        // 655360
  float* valp  = ws + 1310720;       // 655360

  k1_proj<<<dim3(80, 4, 2), 256, 0, stream>>>(query, value, Wq, bq, Wv, bv, u, v, qu, qv, valp);
  k4_attn<<<1280, 256, 0, stream>>>(rpe, key, Wr, br, rnd, seq_len, lex_num, qu, qv, valp, out);
}

// Round 5
// 704.599 us; speedup vs baseline: 1.0132x; 1.0132x over previous
//
#include <hip/hip_runtime.h>

// AdaptSelfAttention: B=4, S=320, H=512, NH=8, DH=64
// B_D = (qv @ Wr_slice) . rpe  -> stream rpe once (839MB, HBM-bound)
// k1: q/v projections -> qu, qv, valp
// k4: prologue (w = qv@Wr into LDS scratch; A_C+rand+c+mask into sc) then
//     stream rpe (swizzled gl_lds, double-buffered), B_D, softmax, PV.
//     R5: R3 loop structure (minimal inter-barrier path) + XCD-swizzled grid.

#define NEGV (-1e15f)

typedef unsigned int u32;

__device__ __forceinline__ void gl_lds16(const float* g, float* l) {
  __builtin_amdgcn_global_load_lds(
      (const __attribute__((address_space(1))) u32*)(g),
      (__attribute__((address_space(3))) u32*)(l), 16, 0, 0);
}

__device__ __forceinline__ float dot4f(const float4 a, const float4 b) {
  return a.x*b.x + a.y*b.y + a.z*b.z + a.w*b.w;
}

// ---------------- K1: q/v projections -> qu, qv, valp ----------------
__global__ __launch_bounds__(256) void k1_proj(
    const float* __restrict__ query, const float* __restrict__ value,
    const float* __restrict__ Wq, const float* __restrict__ bq,
    const float* __restrict__ Wv, const float* __restrict__ bv,
    const float* __restrict__ u, const float* __restrict__ v,
    float* __restrict__ qu, float* __restrict__ qv, float* __restrict__ valp)
{
  const int rt = blockIdx.x;      // 0..79 (16 rows)
  const int ct = blockIdx.y;      // 0..3 (128 cols)
  const int which = blockIdx.z;   // 0: query, 1: value
  const int t = threadIdx.x;
  const int R0 = rt * 16;

  __shared__ float xs[16][516];

  const float* X = which ? value : query;
  const float* W = which ? Wv : Wq;
  const float* bias = which ? bv : bq;

  #pragma unroll
  for (int j = 0; j < 8; ++j) {
    int f4 = t + 256 * j;
    int row = f4 >> 7, c4 = f4 & 127;
    float4 xv = *reinterpret_cast<const float4*>(X + (size_t)(R0 + row) * 512 + c4 * 4);
    *reinterpret_cast<float4*>(&xs[row][c4 * 4]) = xv;
  }
  __syncthreads();

  const int r = t >> 4, clo = t & 15;
  #pragma unroll
  for (int sub = 0; sub < 2; ++sub) {
    const int cb = ct * 128 + sub * 64 + clo * 4;
    float a0 = 0.f, a1 = 0.f, a2 = 0.f, a3 = 0.f;
    const float* w0p = W + (size_t)(cb + 0) * 512;
    const float* w1p = W + (size_t)(cb + 1) * 512;
    const float* w2p = W + (size_t)(cb + 2) * 512;
    const float* w3p = W + (size_t)(cb + 3) * 512;
    #pragma unroll 2
    for (int m4 = 0; m4 < 128; ++m4) {
      float4 x4 = *reinterpret_cast<const float4*>(&xs[r][m4 * 4]);
      float4 w0 = *reinterpret_cast<const float4*>(w0p + m4 * 4);
      float4 w1 = *reinterpret_cast<const float4*>(w1p + m4 * 4);
      float4 w2 = *reinterpret_cast<const float4*>(w2p + m4 * 4);
      float4 w3 = *reinterpret_cast<const float4*>(w3p + m4 * 4);
      a0 += dot4f(x4, w0);
      a1 += dot4f(x4, w1);
      a2 += dot4f(x4, w2);
      a3 += dot4f(x4, w3);
    }
    a0 += bias[cb + 0]; a1 += bias[cb + 1]; a2 += bias[cb + 2]; a3 += bias[cb + 3];
    const size_t ob = (size_t)(R0 + r) * 512 + cb;
    if (which == 0) {
      float4 o1, o2;
      o1.x = a0 + u[cb + 0]; o1.y = a1 + u[cb + 1]; o1.z = a2 + u[cb + 2]; o1.w = a3 + u[cb + 3];
      o2.x = a0 + v[cb + 0]; o2.y = a1 + v[cb + 1]; o2.z = a2 + v[cb + 2]; o2.w = a3 + v[cb + 3];
      *reinterpret_cast<float4*>(qu + ob) = o1;
      *reinterpret_cast<float4*>(qv + ob) = o2;
    } else {
      float4 o; o.x = a0; o.y = a1; o.z = a2; o.w = a3;
      *reinterpret_cast<float4*>(valp + ob) = o;
    }
  }
}

// ---------------- K4: fused prologue + rpe stream + softmax + PV ----------------
// flat grid 1280, XCD-swizzled: xcd=blk&7 -> b=xcd>>1, q=(xcd&1)*160+(blk>>3).
// 256 threads. Wave w owns heads {2w,2w+1}. Tile = 16 k-rows, double-buffered.
__global__ __launch_bounds__(256, 2) void k4_attn(
    const float* __restrict__ rpe, const float* __restrict__ key,
    const float* __restrict__ Wr, const float* __restrict__ br,
    const float* __restrict__ rand_attn,
    const int* __restrict__ seq_len, const int* __restrict__ lex_num,
    const float* __restrict__ qu, const float* __restrict__ qv,
    const float* __restrict__ valp,
    float* __restrict__ out)
{
  const int xcd = blockIdx.x & 7;
  const int idx = blockIdx.x >> 3;          // 0..159
  const int b = xcd >> 1;
  const int q = (xcd & 1) * 160 + idx;
  const int t = threadIdx.x;
  const int w = t >> 6;          // wave 0..3 -> heads 2w, 2w+1
  const int lane = t & 63;
  const int row8 = lane >> 3;    // 0..7
  const int chunk = lane & 7;    // 64-e chunk

  __shared__ float bufA[2][16][512];   // 64 KB, swizzled storage
  __shared__ float sc[8][320];

  const size_t bq = (size_t)b * 320 + q;
  const float* rpe_bq = rpe + bq * 320 * 512;
  float* wscr = &bufA[1][0][0];        // 16 KB scratch for w[8][512] (prologue only)

  // staging source offsets (inverse swizzle), 8 per thread
  int g[8];
  #pragma unroll
  for (int j = 0; j < 8; ++j) {
    int o = (w * 8 + j) * 1024 + lane * 16;   // dest byte in 32KB tile
    int row = o >> 11;
    int ch  = (o >> 8) & 7;
    int win = (o >> 7) & 1;
    int slot = (o >> 4) & 7;
    int i = win * 8 + (slot ^ ((row ^ ch) & 7));
    g[j] = row * 512 + (ch * 16 + i) * 4;     // source float offset
  }

  // stage tile 0 (async; does not touch bufA[1])
  #pragma unroll
  for (int j = 0; j < 8; ++j)
    gl_lds16(rpe_bq + g[j], &bufA[0][0][0] + (w * 8 + j) * 256);

  // ---------------- prologue (hidden under tile-0 staging) ----------------
  const int hh = t >> 5, m = t & 31;           // thread -> (head, slot)
  const float* qv_row = qv + bq * 512 + hh * 64;

  // (1) w[hh][m*16 .. m*16+15] = sum_d qv_row[d] * Wr[hh*64+d][e]
  {
    float4 a4[4];
    #pragma unroll
    for (int ii = 0; ii < 4; ++ii) { a4[ii].x = 0.f; a4[ii].y = 0.f; a4[ii].z = 0.f; a4[ii].w = 0.f; }
    const float* wrb = Wr + (size_t)(hh * 64) * 512 + m * 16;
    #pragma unroll 4
    for (int d = 0; d < 64; ++d) {
      float s = qv_row[d];
      const float4* w4 = reinterpret_cast<const float4*>(wrb + (size_t)d * 512);
      #pragma unroll
      for (int ii = 0; ii < 4; ++ii) {
        a4[ii].x += s * w4[ii].x; a4[ii].y += s * w4[ii].y;
        a4[ii].z += s * w4[ii].z; a4[ii].w += s * w4[ii].w;
      }
    }
    #pragma unroll
    for (int ii = 0; ii < 4; ++ii)
      *reinterpret_cast<float4*>(wscr + hh * 512 + m * 16 + ii * 4) = a4[ii];
  }

  // (2) c = qv_row . br_slice (redundant across the 32 threads of head hh)
  float c = 0.f;
  #pragma unroll 8
  for (int d = 0; d < 64; ++d) c += qv_row[d] * br[hh * 64 + d];

  // (3) A_C + rand + c, masked -> sc[hh][k]  (all 320 k)
  const int len = seq_len[b] + lex_num[0];
  {
    const float* qup = qu + bq * 512 + hh * 64;
    const float* keyb = key + (size_t)b * 320 * 512 + hh * 64;
    const float* rnd_hq = rand_attn + ((size_t)hh * 320 + q) * 320;
    #pragma unroll
    for (int i = 0; i < 10; ++i) {
      const int k = m + 32 * i;
      float val;
      if (k < len) {
        const float* kr = keyb + (size_t)k * 512;
        float a = 0.f;
        #pragma unroll
        for (int ii = 0; ii < 16; ++ii)
          a += dot4f(reinterpret_cast<const float4*>(qup)[ii],
                     reinterpret_cast<const float4*>(kr)[ii]);
        val = a + rnd_hq[k] + c;
      } else {
        val = NEGV;
      }
      sc[hh][k] = val;
    }
  }
  __syncthreads();   // wscr + sc visible; tile-0 staged (vmcnt drain)

  // (4) read w fragments: 2 heads x 16 float4 (this lane's 64-e chunk)
  const int h0 = 2 * w, h1 = 2 * w + 1;
  float4 wc0[16], wc1[16];
  #pragma unroll
  for (int i = 0; i < 16; ++i) {
    wc0[i] = *reinterpret_cast<const float4*>(wscr + h0 * 512 + chunk * 64 + i * 4);
    wc1[i] = *reinterpret_cast<const float4*>(wscr + h1 * 512 + chunk * 64 + i * 4);
  }
  __syncthreads();   // all w reads done before tile-1 staging overwrites bufA[1]

  // ---------------- main streaming loop over 20 tiles of 16 k-rows ----------------
  const int rc = (row8 ^ chunk) & 7;
  const int Cb0 = row8 * 2048 + chunk * 256 + rc * 16;
  const char* bufbase = reinterpret_cast<const char*>(&bufA[0][0][0]);

  int cb = 0;
  for (int tile = 0; tile < 20; ++tile) {
    if (tile + 1 < 20) {
      const float* src = rpe_bq + (size_t)(tile + 1) * 8192;
      float* dst = &bufA[cb ^ 1][0][0];
      #pragma unroll
      for (int j = 0; j < 8; ++j)
        gl_lds16(src + g[j], dst + (w * 8 + j) * 256);
    }

    const char* bufc = bufbase + cb * 32768;
    #pragma unroll
    for (int pass = 0; pass < 2; ++pass) {
      const int C = Cb0 + pass * 16384;
      float a0 = 0.f, a1 = 0.f;
      #pragma unroll
      for (int i = 0; i < 16; ++i) {
        const float4 r4 = *reinterpret_cast<const float4*>(bufc + (C ^ (i << 4)));
        a0 += dot4f(r4, wc0[i]);
        a1 += dot4f(r4, wc1[i]);
      }
      a0 += __shfl_xor(a0, 1, 8);
      a0 += __shfl_xor(a0, 2, 8);
      a0 += __shfl_xor(a0, 4, 8);
      a1 += __shfl_xor(a1, 1, 8);
      a1 += __shfl_xor(a1, 2, 8);
      a1 += __shfl_xor(a1, 4, 8);
      if (chunk == 0) {
        const int kk = tile * 16 + pass * 8 + row8;
        sc[h0][kk] += a0;
        sc[h1][kk] += a1;
      }
    }
    __syncthreads();
    cb ^= 1;
  }

  // ------- softmax per head row -------
  {
    float vals[10];
    float mx = -3.0e38f;
    #pragma unroll
    for (int i = 0; i < 10; ++i) { vals[i] = sc[hh][m + 32 * i]; mx = fmaxf(mx, vals[i]); }
    mx = fmaxf(mx, __shfl_xor(mx, 1, 32));
    mx = fmaxf(mx, __shfl_xor(mx, 2, 32));
    mx = fmaxf(mx, __shfl_xor(mx, 4, 32));
    mx = fmaxf(mx, __shfl_xor(mx, 8, 32));
    mx = fmaxf(mx, __shfl_xor(mx, 16, 32));
    float s = 0.f;
    #pragma unroll
    for (int i = 0; i < 10; ++i) { vals[i] = __expf(vals[i] - mx); s += vals[i]; }
    s += __shfl_xor(s, 1, 32);
    s += __shfl_xor(s, 2, 32);
    s += __shfl_xor(s, 4, 32);
    s += __shfl_xor(s, 8, 32);
    s += __shfl_xor(s, 16, 32);
    const float inv = 1.0f / s;
    #pragma unroll
    for (int i = 0; i < 10; ++i) sc[hh][m + 32 * i] = vals[i] * inv;
  }
  __syncthreads();

  // ------- PV -------
  {
    const int d2 = m;   // d = 2*d2
    float2 a0; a0.x = 0.f; a0.y = 0.f;
    float2 a1; a1.x = 0.f; a1.y = 0.f;
    const float* vb = valp + (size_t)b * 320 * 512 + hh * 64 + d2 * 2;
    #pragma unroll 4
    for (int k = 0; k < 320; k += 2) {
      float p0 = sc[hh][k], p1 = sc[hh][k + 1];
      float2 v0 = *reinterpret_cast<const float2*>(vb + (size_t)k * 512);
      float2 v1 = *reinterpret_cast<const float2*>(vb + (size_t)(k + 1) * 512);
      a0.x += p0 * v0.x; a0.y += p0 * v0.y;
      a1.x += p1 * v1.x; a1.y += p1 * v1.y;
    }
    float2 o; o.x = a0.x + a1.x; o.y = a0.y + a1.y;
    *reinterpret_cast<float2*>(out + bq * 512 + hh * 64 + d2 * 2) = o;
  }
}

extern "C" void kernel_launch(void* const* d_in, const int* in_sizes, int n_in,
                              void* d_out, int out_size, void* d_ws, size_t ws_size,
                              hipStream_t stream) {
  const float* query = (const float*)d_in[0];
  const float* key   = (const float*)d_in[1];
  const float* value = (const float*)d_in[2];
  const float* rpe   = (const float*)d_in[3];
  const int*   seq_len = (const int*)d_in[4];
  const int*   lex_num = (const int*)d_in[5];
  const float* Wq = (const float*)d_in[6];
  const float* bq = (const float*)d_in[7];
  const float* Wv = (const float*)d_in[8];
  const float* bv = (const float*)d_in[9];
  const float* Wr = (const float*)d_in[10];
  const float* br = (const float*)d_in[11];
  const float* u  = (const float*)d_in[12];
  const float* v  = (const float*)d_in[13];
  const float* rnd = (const float*)d_in[14];

  float* out = (float*)d_out;
  float* ws = (float*)d_ws;
  float* qu    = ws;                 // 655360 floats
  float* qv    = ws + 655360;        // 655360
  float* valp  = ws + 1310720;       // 655360

  k1_proj<<<dim3(80, 4, 2), 256, 0, stream>>>(query, value, Wq, bq, Wv, bv, u, v, qu, qv, valp);
  k4_attn<<<1280, 256, 0, stream>>>(rpe, key, Wr, br, rnd, seq_len, lex_num, qu, qv, valp, out);
}

// Round 6
// 687.553 us; speedup vs baseline: 1.0383x; 1.0248x over previous
//
#include <hip/hip_runtime.h>

// AdaptSelfAttention: B=4, S=320, H=512, NH=8, DH=64
// B_D = (qv @ Wr_slice) . rpe  -> stream rpe once (839MB, HBM-bound)
// k1: q/v projections -> qu, qv, valp
// k2: w[b,q,h,e] = qv_slice @ Wr_slice -> w_ws (21MB); c[b,q,h] -> c_ws
// k4: prologue (A_C+rand+c+mask into sc; w frags from w_ws) then stream rpe
//     (swizzled gl_lds, double-buffered), B_D, softmax, PV. Grid (320,4).

#define NEGV (-1e15f)

typedef unsigned int u32;

__device__ __forceinline__ void gl_lds16(const float* g, float* l) {
  __builtin_amdgcn_global_load_lds(
      (const __attribute__((address_space(1))) u32*)(g),
      (__attribute__((address_space(3))) u32*)(l), 16, 0, 0);
}

__device__ __forceinline__ float dot4f(const float4 a, const float4 b) {
  return a.x*b.x + a.y*b.y + a.z*b.z + a.w*b.w;
}

// ---------------- K1: q/v projections -> qu, qv, valp ----------------
__global__ __launch_bounds__(256) void k1_proj(
    const float* __restrict__ query, const float* __restrict__ value,
    const float* __restrict__ Wq, const float* __restrict__ bq,
    const float* __restrict__ Wv, const float* __restrict__ bv,
    const float* __restrict__ u, const float* __restrict__ v,
    float* __restrict__ qu, float* __restrict__ qv, float* __restrict__ valp)
{
  const int rt = blockIdx.x;      // 0..79 (16 rows)
  const int ct = blockIdx.y;      // 0..3 (128 cols)
  const int which = blockIdx.z;   // 0: query, 1: value
  const int t = threadIdx.x;
  const int R0 = rt * 16;

  __shared__ float xs[16][516];

  const float* X = which ? value : query;
  const float* W = which ? Wv : Wq;
  const float* bias = which ? bv : bq;

  #pragma unroll
  for (int j = 0; j < 8; ++j) {
    int f4 = t + 256 * j;
    int row = f4 >> 7, c4 = f4 & 127;
    float4 xv = *reinterpret_cast<const float4*>(X + (size_t)(R0 + row) * 512 + c4 * 4);
    *reinterpret_cast<float4*>(&xs[row][c4 * 4]) = xv;
  }
  __syncthreads();

  const int r = t >> 4, clo = t & 15;
  #pragma unroll
  for (int sub = 0; sub < 2; ++sub) {
    const int cb = ct * 128 + sub * 64 + clo * 4;
    float a0 = 0.f, a1 = 0.f, a2 = 0.f, a3 = 0.f;
    const float* w0p = W + (size_t)(cb + 0) * 512;
    const float* w1p = W + (size_t)(cb + 1) * 512;
    const float* w2p = W + (size_t)(cb + 2) * 512;
    const float* w3p = W + (size_t)(cb + 3) * 512;
    #pragma unroll 2
    for (int m4 = 0; m4 < 128; ++m4) {
      float4 x4 = *reinterpret_cast<const float4*>(&xs[r][m4 * 4]);
      float4 w0 = *reinterpret_cast<const float4*>(w0p + m4 * 4);
      float4 w1 = *reinterpret_cast<const float4*>(w1p + m4 * 4);
      float4 w2 = *reinterpret_cast<const float4*>(w2p + m4 * 4);
      float4 w3 = *reinterpret_cast<const float4*>(w3p + m4 * 4);
      a0 += dot4f(x4, w0);
      a1 += dot4f(x4, w1);
      a2 += dot4f(x4, w2);
      a3 += dot4f(x4, w3);
    }
    a0 += bias[cb + 0]; a1 += bias[cb + 1]; a2 += bias[cb + 2]; a3 += bias[cb + 3];
    const size_t ob = (size_t)(R0 + r) * 512 + cb;
    if (which == 0) {
      float4 o1, o2;
      o1.x = a0 + u[cb + 0]; o1.y = a1 + u[cb + 1]; o1.z = a2 + u[cb + 2]; o1.w = a3 + u[cb + 3];
      o2.x = a0 + v[cb + 0]; o2.y = a1 + v[cb + 1]; o2.z = a2 + v[cb + 2]; o2.w = a3 + v[cb + 3];
      *reinterpret_cast<float4*>(qu + ob) = o1;
      *reinterpret_cast<float4*>(qv + ob) = o2;
    } else {
      float4 o; o.x = a0; o.y = a1; o.z = a2; o.w = a3;
      *reinterpret_cast<float4*>(valp + ob) = o;
    }
  }
}

// ---------------- K2: w[b,q,h,e] = qv_slice @ Wr_slice ; c[b,q,h] ----------------
// grid (80 row-tiles, 8 heads), 256 threads. Wr read ONCE per block (not per q).
__global__ __launch_bounds__(256) void k2_w(
    const float* __restrict__ qv, const float* __restrict__ Wr, const float* __restrict__ br,
    float* __restrict__ w_ws, float* __restrict__ c_ws)
{
  const int rt = blockIdx.x;   // 0..79
  const int h  = blockIdx.y;   // 0..7
  const int t = threadIdx.x;
  const int R0 = rt * 16;

  __shared__ float qs[16][68];
  {
    int row = t >> 4, d4 = t & 15;
    float4 x = *reinterpret_cast<const float4*>(qv + (size_t)(R0 + row) * 512 + h * 64 + d4 * 4);
    *reinterpret_cast<float4*>(&qs[row][d4 * 4]) = x;
  }
  __syncthreads();

  const int r = t >> 4, clo = t & 15;
  #pragma unroll
  for (int sub = 0; sub < 8; ++sub) {
    const int eb = sub * 64 + clo * 4;
    float4 acc; acc.x = 0.f; acc.y = 0.f; acc.z = 0.f; acc.w = 0.f;
    #pragma unroll 4
    for (int d = 0; d < 64; ++d) {
      float s = qs[r][d];
      float4 w4 = *reinterpret_cast<const float4*>(Wr + (size_t)(h * 64 + d) * 512 + eb);
      acc.x += s * w4.x; acc.y += s * w4.y; acc.z += s * w4.z; acc.w += s * w4.w;
    }
    *reinterpret_cast<float4*>(w_ws + (size_t)(R0 + r) * 4096 + h * 512 + eb) = acc;
  }
  if (t < 16) {
    float cs = 0.f;
    for (int d = 0; d < 64; ++d) cs += qs[t][d] * br[h * 64 + d];
    c_ws[(size_t)(R0 + t) * 8 + h] = cs;
  }
}

// ---------------- K4: prologue + rpe stream + softmax + PV ----------------
// grid (320 q, 4 b), 256 threads. Wave w owns heads {2w,2w+1}.
// Tile = 16 k-rows (32KB), double-buffered, XOR-swizzled LDS.
__global__ __launch_bounds__(256, 2) void k4_attn(
    const float* __restrict__ rpe, const float* __restrict__ key,
    const float* __restrict__ rand_attn,
    const int* __restrict__ seq_len, const int* __restrict__ lex_num,
    const float* __restrict__ qu, const float* __restrict__ w_ws,
    const float* __restrict__ c_ws, const float* __restrict__ valp,
    float* __restrict__ out)
{
  const int q = blockIdx.x;
  const int b = blockIdx.y;
  const int t = threadIdx.x;
  const int w = t >> 6;          // wave 0..3 -> heads 2w, 2w+1
  const int lane = t & 63;
  const int row8 = lane >> 3;    // 0..7
  const int chunk = lane & 7;    // 64-e chunk

  __shared__ float bufA[2][16][512];   // 64 KB, swizzled storage
  __shared__ float sc[8][320];

  const size_t bq = (size_t)b * 320 + q;
  const float* rpe_bq = rpe + bq * 320 * 512;

  // staging source offsets (inverse swizzle), 8 per thread
  int g[8];
  #pragma unroll
  for (int j = 0; j < 8; ++j) {
    int o = (w * 8 + j) * 1024 + lane * 16;   // dest byte in 32KB tile
    int row = o >> 11;
    int ch  = (o >> 8) & 7;
    int win = (o >> 7) & 1;
    int slot = (o >> 4) & 7;
    int i = win * 8 + (slot ^ ((row ^ ch) & 7));
    g[j] = row * 512 + (ch * 16 + i) * 4;     // source float offset
  }

  // stage tiles 0 and 1 (async; both buffers free now that wscr is gone)
  #pragma unroll
  for (int j = 0; j < 8; ++j)
    gl_lds16(rpe_bq + g[j], &bufA[0][0][0] + (w * 8 + j) * 256);

  // ---------------- prologue (hidden under tile-0 staging) ----------------
  const int hh = t >> 5, m = t & 31;           // thread -> (head, slot)
  const int h0 = 2 * w, h1 = 2 * w + 1;

  // w fragments straight from w_ws (precomputed by k2): 2 heads x 16 float4
  float4 wc0[16], wc1[16];
  {
    const float* wb0 = w_ws + bq * 4096 + (size_t)h0 * 512 + chunk * 64;
    const float* wb1 = w_ws + bq * 4096 + (size_t)h1 * 512 + chunk * 64;
    #pragma unroll
    for (int i = 0; i < 16; ++i) {
      wc0[i] = *reinterpret_cast<const float4*>(wb0 + i * 4);
      wc1[i] = *reinterpret_cast<const float4*>(wb1 + i * 4);
    }
  }

  const float c = c_ws[bq * 8 + hh];
  const int len = seq_len[b] + lex_num[0];

  // A_C + rand + c, masked -> sc[hh][k]  (all 320 k)
  {
    const float* qup = qu + bq * 512 + hh * 64;
    const float* keyb = key + (size_t)b * 320 * 512 + hh * 64;
    const float* rnd_hq = rand_attn + ((size_t)hh * 320 + q) * 320;
    #pragma unroll
    for (int i = 0; i < 10; ++i) {
      const int k = m + 32 * i;
      float val;
      if (k < len) {
        const float* kr = keyb + (size_t)k * 512;
        float a = 0.f;
        #pragma unroll
        for (int ii = 0; ii < 16; ++ii)
          a += dot4f(reinterpret_cast<const float4*>(qup)[ii],
                     reinterpret_cast<const float4*>(kr)[ii]);
        val = a + rnd_hq[k] + c;
      } else {
        val = NEGV;
      }
      sc[hh][k] = val;
    }
  }
  __syncthreads();   // sc visible; tile-0 staged (vmcnt drain)

  // ---------------- main streaming loop over 20 tiles of 16 k-rows ----------------
  const int rc = (row8 ^ chunk) & 7;
  const int Cb0 = row8 * 2048 + chunk * 256 + rc * 16;
  const char* bufbase = reinterpret_cast<const char*>(&bufA[0][0][0]);

  int cb = 0;
  for (int tile = 0; tile < 20; ++tile) {
    if (tile + 1 < 20) {
      const float* src = rpe_bq + (size_t)(tile + 1) * 8192;
      float* dst = &bufA[cb ^ 1][0][0];
      #pragma unroll
      for (int j = 0; j < 8; ++j)
        gl_lds16(src + g[j], dst + (w * 8 + j) * 256);
    }

    const char* bufc = bufbase + cb * 32768;
    #pragma unroll
    for (int pass = 0; pass < 2; ++pass) {
      const int C = Cb0 + pass * 16384;
      float a0 = 0.f, a1 = 0.f;
      #pragma unroll
      for (int i = 0; i < 16; ++i) {
        const float4 r4 = *reinterpret_cast<const float4*>(bufc + (C ^ (i << 4)));
        a0 += dot4f(r4, wc0[i]);
        a1 += dot4f(r4, wc1[i]);
      }
      a0 += __shfl_xor(a0, 1, 8);
      a0 += __shfl_xor(a0, 2, 8);
      a0 += __shfl_xor(a0, 4, 8);
      a1 += __shfl_xor(a1, 1, 8);
      a1 += __shfl_xor(a1, 2, 8);
      a1 += __shfl_xor(a1, 4, 8);
      if (chunk == 0) {
        const int kk = tile * 16 + pass * 8 + row8;
        sc[h0][kk] += a0;
        sc[h1][kk] += a1;
      }
    }
    __syncthreads();
    cb ^= 1;
  }

  // ------- softmax per head row -------
  {
    float vals[10];
    float mx = -3.0e38f;
    #pragma unroll
    for (int i = 0; i < 10; ++i) { vals[i] = sc[hh][m + 32 * i]; mx = fmaxf(mx, vals[i]); }
    mx = fmaxf(mx, __shfl_xor(mx, 1, 32));
    mx = fmaxf(mx, __shfl_xor(mx, 2, 32));
    mx = fmaxf(mx, __shfl_xor(mx, 4, 32));
    mx = fmaxf(mx, __shfl_xor(mx, 8, 32));
    mx = fmaxf(mx, __shfl_xor(mx, 16, 32));
    float s = 0.f;
    #pragma unroll
    for (int i = 0; i < 10; ++i) { vals[i] = __expf(vals[i] - mx); s += vals[i]; }
    s += __shfl_xor(s, 1, 32);
    s += __shfl_xor(s, 2, 32);
    s += __shfl_xor(s, 4, 32);
    s += __shfl_xor(s, 8, 32);
    s += __shfl_xor(s, 16, 32);
    const float inv = 1.0f / s;
    #pragma unroll
    for (int i = 0; i < 10; ++i) sc[hh][m + 32 * i] = vals[i] * inv;
  }
  __syncthreads();

  // ------- PV -------
  {
    const int d2 = m;   // d = 2*d2
    float2 a0; a0.x = 0.f; a0.y = 0.f;
    float2 a1; a1.x = 0.f; a1.y = 0.f;
    const float* vb = valp + (size_t)b * 320 * 512 + hh * 64 + d2 * 2;
    #pragma unroll 4
    for (int k = 0; k < 320; k += 2) {
      float p0 = sc[hh][k], p1 = sc[hh][k + 1];
      float2 v0 = *reinterpret_cast<const float2*>(vb + (size_t)k * 512);
      float2 v1 = *reinterpret_cast<const float2*>(vb + (size_t)(k + 1) * 512);
      a0.x += p0 * v0.x; a0.y += p0 * v0.y;
      a1.x += p1 * v1.x; a1.y += p1 * v1.y;
    }
    float2 o; o.x = a0.x + a1.x; o.y = a0.y + a1.y;
    *reinterpret_cast<float2*>(out + bq * 512 + hh * 64 + d2 * 2) = o;
  }
}

extern "C" void kernel_launch(void* const* d_in, const int* in_sizes, int n_in,
                              void* d_out, int out_size, void* d_ws, size_t ws_size,
                              hipStream_t stream) {
  const float* query = (const float*)d_in[0];
  const float* key   = (const float*)d_in[1];
  const float* value = (const float*)d_in[2];
  const float* rpe   = (const float*)d_in[3];
  const int*   seq_len = (const int*)d_in[4];
  const int*   lex_num = (const int*)d_in[5];
  const float* Wq = (const float*)d_in[6];
  const float* bq = (const float*)d_in[7];
  const float* Wv = (const float*)d_in[8];
  const float* bv = (const float*)d_in[9];
  const float* Wr = (const float*)d_in[10];
  const float* br = (const float*)d_in[11];
  const float* u  = (const float*)d_in[12];
  const float* v  = (const float*)d_in[13];
  const float* rnd = (const float*)d_in[14];

  float* out = (float*)d_out;
  float* ws = (float*)d_ws;
  float* qu    = ws;                 // 655360 floats
  float* qv    = ws + 655360;        // 655360
  float* valp  = ws + 1310720;       // 655360
  float* w_ws  = ws + 1966080;       // 5242880
  float* c_ws  = ws + 7208960;       // 10240

  k1_proj<<<dim3(80, 4, 2), 256, 0, stream>>>(query, value, Wq, bq, Wv, bv, u, v, qu, qv, valp);
  k2_w<<<dim3(80, 8), 256, 0, stream>>>(qv, Wr, br, w_ws, c_ws);
  k4_attn<<<dim3(320, 4), 256, 0, stream>>>(rpe, key, rnd, seq_len, lex_num, qu, w_ws, c_ws, valp, out);
}